// Round 3
// baseline (21.469 us; speedup 1.0000x reference)
//
#include <hip/hip_runtime.h>

// TensorCPFactorization: value[b] = sum_r prod_i f_i[idx[b,i], r]
// DIM=512, RANK=256, ORDER=4, BATCH=100000, f32 factors.
//
// R3: R2 structure (wave64 per 4 elements, coalesced 1KB row loads) with
// NON-TEMPORAL factor loads. Factor working set (2MB) >> L1 (32KB) so L1
// hit rate is ~1.6%; every miss still allocates a line in L1. If the L1
// fill/evict port is the limiter, `nt` (no-allocate) unlocks the full miss
// path. If instead we're at the per-CU L2-return port (~32B/clk), this is
// neutral and R2's 21.4us is the roofline for the 400MB gather.

#define RANK 256
#define EPW  4   // elements per wave

typedef float f32x4_t __attribute__((ext_vector_type(4)));

__device__ __forceinline__ f32x4_t nt_load4(const float* p) {
    return __builtin_nontemporal_load(reinterpret_cast<const f32x4_t*>(p));
}

__global__ __launch_bounds__(256) void cp_gather_kernel(
    const float* __restrict__ f0, const float* __restrict__ f1,
    const float* __restrict__ f2, const float* __restrict__ f3,
    const int*   __restrict__ idx,
    float*       __restrict__ out, int batch)
{
    const int wid  = (int)((blockIdx.x * blockDim.x + threadIdx.x) >> 6);
    const int lane = (int)(threadIdx.x & 63);
    const int e0   = wid * EPW;
    if (e0 >= batch) return;   // batch % EPW == 0 (100000 % 4)

    const int r = lane * 4;

    // Index vectors for the 4 elements (wave-uniform broadcast loads).
    int4 iv[EPW];
    #pragma unroll
    for (int e = 0; e < EPW; ++e)
        iv[e] = *reinterpret_cast<const int4*>(idx + (size_t)(e0 + e) * 4);

    // Issue all 16 row loads (non-temporal: skip L1 allocation).
    f32x4_t rows[EPW][4];
    #pragma unroll
    for (int e = 0; e < EPW; ++e) {
        rows[e][0] = nt_load4(f0 + (size_t)iv[e].x * RANK + r);
        rows[e][1] = nt_load4(f1 + (size_t)iv[e].y * RANK + r);
        rows[e][2] = nt_load4(f2 + (size_t)iv[e].z * RANK + r);
        rows[e][3] = nt_load4(f3 + (size_t)iv[e].w * RANK + r);
    }

    // Per-lane 4-wide dot for each element.
    float s[EPW];
    #pragma unroll
    for (int e = 0; e < EPW; ++e) {
        const f32x4_t a = rows[e][0], b = rows[e][1], c = rows[e][2], d = rows[e][3];
        s[e] = a.x * b.x * c.x * d.x
             + a.y * b.y * c.y * d.y
             + a.z * b.z * c.z * d.z
             + a.w * b.w * c.w * d.w;
    }

    // 4 independent 64-lane butterfly reductions.
    #pragma unroll
    for (int off = 32; off > 0; off >>= 1) {
        #pragma unroll
        for (int e = 0; e < EPW; ++e)
            s[e] += __shfl_xor(s[e], off);
    }

    if (lane == 0)
        *reinterpret_cast<float4*>(out + e0) = make_float4(s[0], s[1], s[2], s[3]);
}

extern "C" void kernel_launch(void* const* d_in, const int* in_sizes, int n_in,
                              void* d_out, int out_size, void* d_ws, size_t ws_size,
                              hipStream_t stream) {
    const float* f0  = (const float*)d_in[0];
    const float* f1  = (const float*)d_in[1];
    const float* f2  = (const float*)d_in[2];
    const float* f3  = (const float*)d_in[3];
    const int*   idx = (const int*)d_in[4];
    float* out = (float*)d_out;

    const int batch = out_size;
    const int threads = 256;                           // 4 waves / block
    const int elems_per_block = (threads / 64) * EPW;  // 16
    const int grid = (batch + elems_per_block - 1) / elems_per_block;

    cp_gather_kernel<<<grid, threads, 0, stream>>>(f0, f1, f2, f3, idx, out, batch);
}

// Round 4
// 20.432 us; speedup vs baseline: 1.0508x; 1.0508x over previous
//
#include <hip/hip_runtime.h>
#include <hip/hip_fp16.h>

// TensorCPFactorization: value[b] = sum_r prod_i f_i[idx[b,i], r]
// DIM=512, RANK=256, ORDER=4, BATCH=100000, f32 factors.
//
// R4: the kernel is L2-return-port bound (R2/R3: ~31 B/clk/CU, nt-neutral).
// Cut the 400 MB gather stream in half by converting factors to f16 in d_ws
// (pass 1, 3 MB traffic), then gathering f16 rows (512 B each). Layout:
// half-wave (32 lanes) per row, 16 B/lane -> load-instr count per byte equals
// the f32 kernel; 8 elements per wave; 5-step butterfly reduction per half.
// Accuracy: f16 RTNE adds ~1e-9 max output error vs 2.06e-8 threshold.

#define RANK   256
#define FELEMS (512 * 256)   // elements per factor
#define EPW    8             // elements per wave (4 pairs)

// ---- pass 1: f32 -> f16 conversion into d_ws ------------------------------
__global__ __launch_bounds__(256) void cp_convert_f16(
    const float* __restrict__ f0, const float* __restrict__ f1,
    const float* __restrict__ f2, const float* __restrict__ f3,
    __half* __restrict__ ws)
{
    const float* srcs[4] = {f0, f1, f2, f3};
    const float* __restrict__ src = srcs[blockIdx.y];
    __half* __restrict__ dst = ws + (size_t)blockIdx.y * FELEMS;

    const int base = (blockIdx.x * 256 + threadIdx.x) * 8;
    if (base >= FELEMS) return;

    const float4 a = *reinterpret_cast<const float4*>(src + base);
    const float4 b = *reinterpret_cast<const float4*>(src + base + 4);
    union { uint4 u; __half2 h[4]; } pk;
    pk.h[0] = __float22half2_rn(make_float2(a.x, a.y));
    pk.h[1] = __float22half2_rn(make_float2(a.z, a.w));
    pk.h[2] = __float22half2_rn(make_float2(b.x, b.y));
    pk.h[3] = __float22half2_rn(make_float2(b.z, b.w));
    *reinterpret_cast<uint4*>(dst + base) = pk.u;
}

// ---- pass 2: gather + dot over f16 rows -----------------------------------
__device__ __forceinline__ void cvt8(const uint4 u, float* v) {
    const __half2* h = reinterpret_cast<const __half2*>(&u);
    float2 t;
    t = __half22float2(h[0]); v[0] = t.x; v[1] = t.y;
    t = __half22float2(h[1]); v[2] = t.x; v[3] = t.y;
    t = __half22float2(h[2]); v[4] = t.x; v[5] = t.y;
    t = __half22float2(h[3]); v[6] = t.x; v[7] = t.y;
}

__global__ __launch_bounds__(256) void cp_gather_f16(
    const __half* __restrict__ ws, const int* __restrict__ idx,
    float* __restrict__ out, int batch)
{
    const int wid  = (int)((blockIdx.x * blockDim.x + threadIdx.x) >> 6);
    const int lane = (int)(threadIdx.x & 63);
    const int e0   = wid * EPW;
    if (e0 >= batch) return;

    const int half_id = lane >> 5;       // which element of each pair
    const int l5      = lane & 31;
    const int r0      = l5 * 8;          // 8 rank entries per lane

    // element indices (divergent between half-waves: 2 broadcasts per load)
    int  ee[4];
    int4 iv[4];
    #pragma unroll
    for (int p = 0; p < 4; ++p) {
        ee[p] = e0 + 2 * p + half_id;
        const int ec = ee[p] < batch ? ee[p] : batch - 1;
        iv[p] = *reinterpret_cast<const int4*>(idx + (size_t)ec * 4);
    }

    // 16 x dwordx4 loads: each covers 2 rows (one per half-wave), 512 B/row
    uint4 raw[4][4];
    #pragma unroll
    for (int p = 0; p < 4; ++p) {
        raw[p][0] = *reinterpret_cast<const uint4*>(ws + 0 * FELEMS + (size_t)iv[p].x * RANK + r0);
        raw[p][1] = *reinterpret_cast<const uint4*>(ws + 1 * FELEMS + (size_t)iv[p].y * RANK + r0);
        raw[p][2] = *reinterpret_cast<const uint4*>(ws + 2 * FELEMS + (size_t)iv[p].z * RANK + r0);
        raw[p][3] = *reinterpret_cast<const uint4*>(ws + 3 * FELEMS + (size_t)iv[p].w * RANK + r0);
    }

    float s[4];
    #pragma unroll
    for (int p = 0; p < 4; ++p) {
        float va[8], vb[8], vc[8], vd[8];
        cvt8(raw[p][0], va);
        cvt8(raw[p][1], vb);
        cvt8(raw[p][2], vc);
        cvt8(raw[p][3], vd);
        float acc = 0.f;
        #pragma unroll
        for (int k = 0; k < 8; ++k)
            acc += va[k] * vb[k] * vc[k] * vd[k];
        s[p] = acc;
    }

    // 5-step butterfly within each 32-lane half (4 independent chains)
    #pragma unroll
    for (int off = 16; off > 0; off >>= 1) {
        #pragma unroll
        for (int p = 0; p < 4; ++p)
            s[p] += __shfl_xor(s[p], off);
    }

    if (l5 == 0) {
        #pragma unroll
        for (int p = 0; p < 4; ++p)
            if (ee[p] < batch) out[ee[p]] = s[p];
    }
}

// ---- fallback: R2 f32 kernel (used only if ws is too small) ---------------
__global__ __launch_bounds__(256) void cp_gather_f32(
    const float* __restrict__ f0, const float* __restrict__ f1,
    const float* __restrict__ f2, const float* __restrict__ f3,
    const int*   __restrict__ idx,
    float*       __restrict__ out, int batch)
{
    const int wid  = (int)((blockIdx.x * blockDim.x + threadIdx.x) >> 6);
    const int lane = (int)(threadIdx.x & 63);
    const int e0   = wid * 4;
    if (e0 >= batch) return;
    const int r = lane * 4;
    float s[4];
    #pragma unroll
    for (int e = 0; e < 4; ++e) {
        const int  ec = (e0 + e) < batch ? (e0 + e) : batch - 1;
        const int4 iv = *reinterpret_cast<const int4*>(idx + (size_t)ec * 4);
        const float4 a = *reinterpret_cast<const float4*>(f0 + (size_t)iv.x * RANK + r);
        const float4 b = *reinterpret_cast<const float4*>(f1 + (size_t)iv.y * RANK + r);
        const float4 c = *reinterpret_cast<const float4*>(f2 + (size_t)iv.z * RANK + r);
        const float4 d = *reinterpret_cast<const float4*>(f3 + (size_t)iv.w * RANK + r);
        s[e] = a.x * b.x * c.x * d.x + a.y * b.y * c.y * d.y
             + a.z * b.z * c.z * d.z + a.w * b.w * c.w * d.w;
    }
    #pragma unroll
    for (int off = 32; off > 0; off >>= 1)
        #pragma unroll
        for (int e = 0; e < 4; ++e)
            s[e] += __shfl_xor(s[e], off);
    if (lane == 0)
        #pragma unroll
        for (int e = 0; e < 4; ++e)
            if (e0 + e < batch) out[e0 + e] = s[e];
}

extern "C" void kernel_launch(void* const* d_in, const int* in_sizes, int n_in,
                              void* d_out, int out_size, void* d_ws, size_t ws_size,
                              hipStream_t stream) {
    const float* f0  = (const float*)d_in[0];
    const float* f1  = (const float*)d_in[1];
    const float* f2  = (const float*)d_in[2];
    const float* f3  = (const float*)d_in[3];
    const int*   idx = (const int*)d_in[4];
    float* out = (float*)d_out;
    const int batch = out_size;

    const size_t ws_needed = (size_t)4 * FELEMS * sizeof(__half);  // 1 MiB
    if (ws_size >= ws_needed) {
        __half* wsf = (__half*)d_ws;
        // pass 1: convert 4 factors to f16
        dim3 cgrid(FELEMS / (256 * 8), 4);       // 64 x 4 blocks
        cp_convert_f16<<<cgrid, 256, 0, stream>>>(f0, f1, f2, f3, wsf);
        // pass 2: gather
        const int waves = (batch + EPW - 1) / EPW;
        const int grid  = (waves + 3) / 4;       // 4 waves / block
        cp_gather_f16<<<grid, 256, 0, stream>>>(wsf, idx, out, batch);
    } else {
        const int grid = (batch + 15) / 16;
        cp_gather_f32<<<grid, 256, 0, stream>>>(f0, f1, f2, f3, idx, out, batch);
    }
}